// Round 3
// baseline (533.149 us; speedup 1.0000x reference)
//
#include <hip/hip_runtime.h>

#define N_NODES 100000
#define N_EDGES 1600000
#define D 64
#define SCAN_BLK 1024
#define N_SCAN_BLKS ((N_NODES + SCAN_BLK - 1) / SCAN_BLK)   // 98
#define NWAVES 16                                            // nodes per block

// ---------------------------------------------------------------------------
// 1) Degree histogram
// ---------------------------------------------------------------------------
__global__ __launch_bounds__(256) void degree_kernel(const int* __restrict__ dst,
                                                     int* __restrict__ deg) {
    int e = blockIdx.x * blockDim.x + threadIdx.x;
    if (e < N_EDGES) atomicAdd(&deg[dst[e]], 1);
}

// ---------------------------------------------------------------------------
// 2a) Per-block exclusive scan of deg, block sums out
// ---------------------------------------------------------------------------
__global__ __launch_bounds__(SCAN_BLK) void scan_blocks(const int* __restrict__ deg,
                                                        int* __restrict__ ex,
                                                        int* __restrict__ blk_sum) {
    __shared__ int tmp[SCAN_BLK];
    int i = blockIdx.x * SCAN_BLK + threadIdx.x;
    int v = (i < N_NODES) ? deg[i] : 0;
    int val = v;
    tmp[threadIdx.x] = val;
    __syncthreads();
    for (int off = 1; off < SCAN_BLK; off <<= 1) {
        int t = (threadIdx.x >= off) ? tmp[threadIdx.x - off] : 0;
        __syncthreads();
        val += t;
        tmp[threadIdx.x] = val;
        __syncthreads();
    }
    if (i < N_NODES) ex[i] = val - v;
    if (threadIdx.x == SCAN_BLK - 1) blk_sum[blockIdx.x] = val;
}

// 2b) Parallel exclusive scan of the 98 block sums (128-thread LDS scan)
__global__ __launch_bounds__(128) void scan_partials(const int* __restrict__ blk_sum,
                                                     int* __restrict__ blk_off) {
    __shared__ int t[128];
    int i = threadIdx.x;
    int v = (i < N_SCAN_BLKS) ? blk_sum[i] : 0;
    int val = v;
    t[i] = val;
    __syncthreads();
    for (int off = 1; off < 128; off <<= 1) {
        int u = (i >= off) ? t[i - off] : 0;
        __syncthreads();
        val += u;
        t[i] = val;
        __syncthreads();
    }
    if (i < N_SCAN_BLKS) blk_off[i] = val - v;   // exclusive
}

// 2c) row_ptr = ex + blk_off; cursor = copy; row_ptr[N] = E
__global__ __launch_bounds__(256) void finalize_rowptr(const int* __restrict__ ex,
                                                       const int* __restrict__ blk_off,
                                                       int* __restrict__ row_ptr,
                                                       int* __restrict__ cursor) {
    int i = blockIdx.x * blockDim.x + threadIdx.x;
    if (i < N_NODES) {
        int v = ex[i] + blk_off[i >> 10];
        row_ptr[i] = v;
        cursor[i]  = v;
    } else if (i == N_NODES) {
        row_ptr[N_NODES] = N_EDGES;
    }
}

// ---------------------------------------------------------------------------
// 3) Counting-sort fill. Nontemporal store: each 4B store dirties a full line
//    anyway (WRITE_SIZE ~ E*64B measured); keep those lines out of L2.
// ---------------------------------------------------------------------------
__global__ __launch_bounds__(256) void fill_kernel(const int* __restrict__ src,
                                                   const int* __restrict__ dst,
                                                   int* __restrict__ cursor,
                                                   int* __restrict__ sorted_src) {
    int e = blockIdx.x * blockDim.x + threadIdx.x;
    if (e < N_EDGES) {
        int p = atomicAdd(&cursor[dst[e]], 1);
        __builtin_nontemporal_store(src[e], &sorted_src[p]);
    }
}

// ---------------------------------------------------------------------------
// 4) Fused SAGE layer, one wave per node.
//    Gather: lane = (g = lane>>4) x (c = lane&15). Each instruction reads
//    float4 for 4 neighbor rows at once (1 KB/instr, 4x round 2); 16-neighbor
//    unroll for MLP. Cross-group reduce via shfl_xor(16/32).
//    GEMM: weights row-major [o][k] in LDS, stride 72 (o*18 mod 32 covers all
//    16 even bank residues -> balanced 8 acc/bank, b128 structural minimum);
//    lane o reads 4 k's per ds_read_b128; mean/x are broadcast float4 reads.
// ---------------------------------------------------------------------------
__global__ __launch_bounds__(NWAVES * 64) void sage_layer(
    const int* __restrict__ row_ptr, const int* __restrict__ nbr,
    const float* __restrict__ feat,
    const float* __restrict__ w_l, const float* __restrict__ b_l,
    const float* __restrict__ w_r,
    float* __restrict__ out, int apply_relu)
{
    __shared__ float wl_s[D * 72];            // 18 KB
    __shared__ float wr_s[D * 72];            // 18 KB
    __shared__ float bias[D];
    __shared__ float mean_s[NWAVES][D];       // 4 KB
    __shared__ float x_s[NWAVES][D];          // 4 KB

    int tid = threadIdx.x;
    for (int i = tid; i < D * D; i += NWAVES * 64) {
        int o = i >> 6, k = i & 63;
        wl_s[o * 72 + k] = w_l[i];
        wr_s[o * 72 + k] = w_r[i];
    }
    if (tid < D) bias[tid] = b_l[tid];
    __syncthreads();

    int wave = tid >> 6;
    int lane = tid & 63;
    int node = blockIdx.x * NWAVES + wave;
    if (node >= N_NODES) return;

    int g = lane >> 4;       // neighbor group 0..3
    int c = lane & 15;       // column quad 0..15

    int begin = row_ptr[node];
    int end   = row_ptr[node + 1];

    float4 acc4 = make_float4(0.f, 0.f, 0.f, 0.f);
    for (int base = begin; base < end; base += 64) {
        int m = end - base; if (m > 64) m = 64;
        int id = (lane < m) ? nbr[base + lane] : 0;
        int j = 0;
        // 16 neighbors per iteration: group g takes rows j+g, j+4+g, j+8+g, j+12+g
        for (; j + 16 <= m; j += 16) {
            int s0 = __shfl(id, j + g, 64);
            int s1 = __shfl(id, j + 4 + g, 64);
            int s2 = __shfl(id, j + 8 + g, 64);
            int s3 = __shfl(id, j + 12 + g, 64);
            float4 v0 = *(const float4*)&feat[(size_t)s0 * D + 4 * c];
            float4 v1 = *(const float4*)&feat[(size_t)s1 * D + 4 * c];
            float4 v2 = *(const float4*)&feat[(size_t)s2 * D + 4 * c];
            float4 v3 = *(const float4*)&feat[(size_t)s3 * D + 4 * c];
            acc4.x += (v0.x + v1.x) + (v2.x + v3.x);
            acc4.y += (v0.y + v1.y) + (v2.y + v3.y);
            acc4.z += (v0.z + v1.z) + (v2.z + v3.z);
            acc4.w += (v0.w + v1.w) + (v2.w + v3.w);
        }
        for (; j + 4 <= m; j += 4) {
            int s = __shfl(id, j + g, 64);
            float4 v = *(const float4*)&feat[(size_t)s * D + 4 * c];
            acc4.x += v.x; acc4.y += v.y; acc4.z += v.z; acc4.w += v.w;
        }
        int rem = m - j;     // 0..3; group r handles neighbor j+r
        if (rem > 0) {
            int s = __shfl(id, j + g, 64);
            if (g < rem) {
                float4 v = *(const float4*)&feat[(size_t)s * D + 4 * c];
                acc4.x += v.x; acc4.y += v.y; acc4.z += v.z; acc4.w += v.w;
            }
        }
    }

    // Reduce across the 4 neighbor groups
    acc4.x += __shfl_xor(acc4.x, 16, 64);
    acc4.y += __shfl_xor(acc4.y, 16, 64);
    acc4.z += __shfl_xor(acc4.z, 16, 64);
    acc4.w += __shfl_xor(acc4.w, 16, 64);
    acc4.x += __shfl_xor(acc4.x, 32, 64);
    acc4.y += __shfl_xor(acc4.y, 32, 64);
    acc4.z += __shfl_xor(acc4.z, 32, 64);
    acc4.w += __shfl_xor(acc4.w, 32, 64);

    int   deg = end - begin;
    float inv = 1.0f / fmaxf((float)deg, 1.0f);

    float4 x4 = *(const float4*)&feat[(size_t)node * D + 4 * c];
    if (g == 0) {
        float4 m4 = make_float4(acc4.x * inv, acc4.y * inv, acc4.z * inv, acc4.w * inv);
        *(float4*)&mean_s[wave][4 * c] = m4;
        *(float4*)&x_s[wave][4 * c]    = x4;
    }
    // Wave-local LDS write->read: same-wave ordering via compiler lgkmcnt.

    int o = lane;
    float acc = bias[o];
    const float4* wl4p = (const float4*)&wl_s[o * 72];
    const float4* wr4p = (const float4*)&wr_s[o * 72];
    const float4* m4p  = (const float4*)&mean_s[wave][0];
    const float4* x4p  = (const float4*)&x_s[wave][0];
#pragma unroll
    for (int kq = 0; kq < 16; ++kq) {
        float4 wl4 = wl4p[kq];
        float4 wr4 = wr4p[kq];
        float4 m4  = m4p[kq];      // broadcast (same addr all lanes)
        float4 xx4 = x4p[kq];
        acc += m4.x * wl4.x + m4.y * wl4.y + m4.z * wl4.z + m4.w * wl4.w;
        acc += xx4.x * wr4.x + xx4.y * wr4.y + xx4.z * wr4.z + xx4.w * wr4.w;
    }
    if (apply_relu) acc = fmaxf(acc, 0.0f);
    out[(size_t)node * D + o] = acc;
}

// ---------------------------------------------------------------------------
// Launch
// ---------------------------------------------------------------------------
extern "C" void kernel_launch(void* const* d_in, const int* in_sizes, int n_in,
                              void* d_out, int out_size, void* d_ws, size_t ws_size,
                              hipStream_t stream) {
    const float* x    = (const float*)d_in[0];
    const int*   ei   = (const int*)d_in[1];   // [2, E]: src = ei, dst = ei + E
    const float* w_l1 = (const float*)d_in[2];
    const float* b_l1 = (const float*)d_in[3];
    const float* w_r1 = (const float*)d_in[4];
    const float* w_l2 = (const float*)d_in[5];
    const float* b_l2 = (const float*)d_in[6];
    const float* w_r2 = (const float*)d_in[7];
    float* out = (float*)d_out;

    const int* src = ei;
    const int* dst = ei + N_EDGES;

    int* deg        = (int*)d_ws;                    // N
    int* ex         = deg + N_NODES;                 // N
    int* blk_sum    = ex + N_NODES;                  // 128
    int* blk_off    = blk_sum + 128;                 // 128
    int* row_ptr    = blk_off + 128;                 // N + 1
    int* cursor     = row_ptr + (N_NODES + 1);       // N
    int* sorted_src = cursor + N_NODES;              // E
    float* h        = (float*)(sorted_src + N_EDGES);// N * D

    hipMemsetAsync(deg, 0, (size_t)N_NODES * sizeof(int), stream);

    dim3 blk(256);
    degree_kernel<<<dim3((N_EDGES + 255) / 256), blk, 0, stream>>>(dst, deg);
    scan_blocks<<<dim3(N_SCAN_BLKS), dim3(SCAN_BLK), 0, stream>>>(deg, ex, blk_sum);
    scan_partials<<<dim3(1), dim3(128), 0, stream>>>(blk_sum, blk_off);
    finalize_rowptr<<<dim3((N_NODES + 1 + 255) / 256), blk, 0, stream>>>(ex, blk_off, row_ptr, cursor);
    fill_kernel<<<dim3((N_EDGES + 255) / 256), blk, 0, stream>>>(src, dst, cursor, sorted_src);

    dim3 lblk(NWAVES * 64);
    dim3 lgrid((N_NODES + NWAVES - 1) / NWAVES);
    sage_layer<<<lgrid, lblk, 0, stream>>>(row_ptr, sorted_src, x, w_l1, b_l1, w_r1, h, 1);
    sage_layer<<<lgrid, lblk, 0, stream>>>(row_ptr, sorted_src, h, w_l2, b_l2, w_r2, out, 0);
}

// Round 4
// 494.672 us; speedup vs baseline: 1.0778x; 1.0778x over previous
//
#include <hip/hip_runtime.h>

#define N_NODES 100000
#define N_EDGES 1600000
#define D 64
#define SCAN_BLK 1024
#define N_SCAN_BLKS ((N_NODES + SCAN_BLK - 1) / SCAN_BLK)   // 98
#define NWAVES 16                                            // nodes per block
#define WSTRIDE 68   // 68 mod 32 = 4 -> b128 start banks 4(o+k)%32: 8 starts tiling all 32 banks

// round-to-nearest-even fp32 -> bf16 bits
__device__ __forceinline__ unsigned short f2bf(float f) {
    unsigned u = __float_as_uint(f);
    u = (u + 0x7fffu + ((u >> 16) & 1u)) >> 16;
    return (unsigned short)u;
}

// accumulate 4 bf16 (packed in uint2) into float4
__device__ __forceinline__ void acc_bf16x4(float4& a, uint2 v) {
    a.x += __uint_as_float(v.x << 16);
    a.y += __uint_as_float(v.x & 0xffff0000u);
    a.z += __uint_as_float(v.y << 16);
    a.w += __uint_as_float(v.y & 0xffff0000u);
}

// ---------------------------------------------------------------------------
// 0) Cast x (fp32) -> xb (bf16). Thread = 4 elements.
// ---------------------------------------------------------------------------
__global__ __launch_bounds__(256) void cast_kernel(const float* __restrict__ x,
                                                   unsigned short* __restrict__ xb) {
    int i = blockIdx.x * blockDim.x + threadIdx.x;          // quad index
    if (i < N_NODES * D / 4) {
        float4 v = ((const float4*)x)[i];
        ushort4 o;
        o.x = f2bf(v.x); o.y = f2bf(v.y); o.z = f2bf(v.z); o.w = f2bf(v.w);
        ((ushort4*)xb)[i] = o;
    }
}

// ---------------------------------------------------------------------------
// 1) Degree histogram
// ---------------------------------------------------------------------------
__global__ __launch_bounds__(256) void degree_kernel(const int* __restrict__ dst,
                                                     int* __restrict__ deg) {
    int e = blockIdx.x * blockDim.x + threadIdx.x;
    if (e < N_EDGES) atomicAdd(&deg[dst[e]], 1);
}

// ---------------------------------------------------------------------------
// 2a) Per-block exclusive scan of deg, block sums out
// ---------------------------------------------------------------------------
__global__ __launch_bounds__(SCAN_BLK) void scan_blocks(const int* __restrict__ deg,
                                                        int* __restrict__ ex,
                                                        int* __restrict__ blk_sum) {
    __shared__ int tmp[SCAN_BLK];
    int i = blockIdx.x * SCAN_BLK + threadIdx.x;
    int v = (i < N_NODES) ? deg[i] : 0;
    int val = v;
    tmp[threadIdx.x] = val;
    __syncthreads();
    for (int off = 1; off < SCAN_BLK; off <<= 1) {
        int t = (threadIdx.x >= off) ? tmp[threadIdx.x - off] : 0;
        __syncthreads();
        val += t;
        tmp[threadIdx.x] = val;
        __syncthreads();
    }
    if (i < N_NODES) ex[i] = val - v;
    if (threadIdx.x == SCAN_BLK - 1) blk_sum[blockIdx.x] = val;
}

// 2b) scan of the 98 block sums
__global__ __launch_bounds__(128) void scan_partials(const int* __restrict__ blk_sum,
                                                     int* __restrict__ blk_off) {
    __shared__ int t[128];
    int i = threadIdx.x;
    int v = (i < N_SCAN_BLKS) ? blk_sum[i] : 0;
    int val = v;
    t[i] = val;
    __syncthreads();
    for (int off = 1; off < 128; off <<= 1) {
        int u = (i >= off) ? t[i - off] : 0;
        __syncthreads();
        val += u;
        t[i] = val;
        __syncthreads();
    }
    if (i < N_SCAN_BLKS) blk_off[i] = val - v;
}

// 2c) row_ptr = ex + blk_off; cursor = copy; row_ptr[N] = E
__global__ __launch_bounds__(256) void finalize_rowptr(const int* __restrict__ ex,
                                                       const int* __restrict__ blk_off,
                                                       int* __restrict__ row_ptr,
                                                       int* __restrict__ cursor) {
    int i = blockIdx.x * blockDim.x + threadIdx.x;
    if (i < N_NODES) {
        int v = ex[i] + blk_off[i >> 10];
        row_ptr[i] = v;
        cursor[i]  = v;
    } else if (i == N_NODES) {
        row_ptr[N_NODES] = N_EDGES;
    }
}

// ---------------------------------------------------------------------------
// 3) Counting-sort fill (nontemporal scattered store)
// ---------------------------------------------------------------------------
__global__ __launch_bounds__(256) void fill_kernel(const int* __restrict__ src,
                                                   const int* __restrict__ dst,
                                                   int* __restrict__ cursor,
                                                   int* __restrict__ sorted_src) {
    int e = blockIdx.x * blockDim.x + threadIdx.x;
    if (e < N_EDGES) {
        int p = atomicAdd(&cursor[dst[e]], 1);
        __builtin_nontemporal_store(src[e], &sorted_src[p]);
    }
}

// ---------------------------------------------------------------------------
// 4) Fused SAGE layer. Gather from bf16 table (halves fetch-bound bytes);
//    self row, accumulation, mean, GEMM all fp32.
//    Lane layout: g = lane>>4 (neighbor group), c = lane&15 (column quad).
//    One load instruction = 4 rows x 128B (bf16 rows).
//    Optionally emits bf16 copy of output (gather table for next layer).
// ---------------------------------------------------------------------------
__global__ __launch_bounds__(NWAVES * 64) void sage_layer(
    const int* __restrict__ row_ptr, const int* __restrict__ nbr,
    const unsigned short* __restrict__ featb,   // bf16 gather table
    const float* __restrict__ feat,             // fp32 (self rows)
    const float* __restrict__ w_l, const float* __restrict__ b_l,
    const float* __restrict__ w_r,
    float* __restrict__ out,
    unsigned short* __restrict__ outb,          // bf16 out (or nullptr)
    int apply_relu)
{
    __shared__ float wl_s[D * WSTRIDE];
    __shared__ float wr_s[D * WSTRIDE];
    __shared__ float bias[D];
    __shared__ float mean_s[NWAVES][D];
    __shared__ float x_s[NWAVES][D];

    int tid = threadIdx.x;
    for (int i = tid; i < D * D; i += NWAVES * 64) {
        int o = i >> 6, k = i & 63;
        wl_s[o * WSTRIDE + k] = w_l[i];
        wr_s[o * WSTRIDE + k] = w_r[i];
    }
    if (tid < D) bias[tid] = b_l[tid];
    __syncthreads();

    int wave = tid >> 6;
    int lane = tid & 63;
    int node = blockIdx.x * NWAVES + wave;
    if (node >= N_NODES) return;

    int g = lane >> 4;       // neighbor group 0..3
    int c = lane & 15;       // column quad 0..15

    int begin = row_ptr[node];
    int end   = row_ptr[node + 1];

    float4 acc4 = make_float4(0.f, 0.f, 0.f, 0.f);
    for (int base = begin; base < end; base += 64) {
        int m = end - base; if (m > 64) m = 64;
        int id = (lane < m) ? nbr[base + lane] : 0;
        int j = 0;
        for (; j + 16 <= m; j += 16) {
            int s0 = __shfl(id, j + g, 64);
            int s1 = __shfl(id, j + 4 + g, 64);
            int s2 = __shfl(id, j + 8 + g, 64);
            int s3 = __shfl(id, j + 12 + g, 64);
            uint2 v0 = *(const uint2*)&featb[(size_t)s0 * D + 4 * c];
            uint2 v1 = *(const uint2*)&featb[(size_t)s1 * D + 4 * c];
            uint2 v2 = *(const uint2*)&featb[(size_t)s2 * D + 4 * c];
            uint2 v3 = *(const uint2*)&featb[(size_t)s3 * D + 4 * c];
            acc_bf16x4(acc4, v0);
            acc_bf16x4(acc4, v1);
            acc_bf16x4(acc4, v2);
            acc_bf16x4(acc4, v3);
        }
        for (; j + 4 <= m; j += 4) {
            int s = __shfl(id, j + g, 64);
            uint2 v = *(const uint2*)&featb[(size_t)s * D + 4 * c];
            acc_bf16x4(acc4, v);
        }
        int rem = m - j;     // 0..3; group r handles neighbor j+r
        if (rem > 0) {
            int s = __shfl(id, j + g, 64);
            if (g < rem) {
                uint2 v = *(const uint2*)&featb[(size_t)s * D + 4 * c];
                acc_bf16x4(acc4, v);
            }
        }
    }

    // Reduce across the 4 neighbor groups
    acc4.x += __shfl_xor(acc4.x, 16, 64);
    acc4.y += __shfl_xor(acc4.y, 16, 64);
    acc4.z += __shfl_xor(acc4.z, 16, 64);
    acc4.w += __shfl_xor(acc4.w, 16, 64);
    acc4.x += __shfl_xor(acc4.x, 32, 64);
    acc4.y += __shfl_xor(acc4.y, 32, 64);
    acc4.z += __shfl_xor(acc4.z, 32, 64);
    acc4.w += __shfl_xor(acc4.w, 32, 64);

    int   deg = end - begin;
    float inv = 1.0f / fmaxf((float)deg, 1.0f);

    float4 x4 = *(const float4*)&feat[(size_t)node * D + 4 * c];   // fp32 self row
    if (g == 0) {
        float4 m4 = make_float4(acc4.x * inv, acc4.y * inv, acc4.z * inv, acc4.w * inv);
        *(float4*)&mean_s[wave][4 * c] = m4;
        *(float4*)&x_s[wave][4 * c]    = x4;
    }
    // Wave-local LDS write->read ordering via compiler lgkmcnt.

    int o = lane;
    float acc = bias[o];
    const float4* wl4p = (const float4*)&wl_s[o * WSTRIDE];
    const float4* wr4p = (const float4*)&wr_s[o * WSTRIDE];
    const float4* m4p  = (const float4*)&mean_s[wave][0];
    const float4* x4p  = (const float4*)&x_s[wave][0];
#pragma unroll
    for (int kq = 0; kq < 16; ++kq) {
        float4 wl4 = wl4p[kq];
        float4 wr4 = wr4p[kq];
        float4 m4  = m4p[kq];      // broadcast (same addr all lanes)
        float4 xx4 = x4p[kq];
        acc += m4.x * wl4.x + m4.y * wl4.y + m4.z * wl4.z + m4.w * wl4.w;
        acc += xx4.x * wr4.x + xx4.y * wr4.y + xx4.z * wr4.z + xx4.w * wr4.w;
    }
    if (apply_relu) acc = fmaxf(acc, 0.0f);
    out[(size_t)node * D + o] = acc;
    if (outb) outb[(size_t)node * D + o] = f2bf(acc);
}

// ---------------------------------------------------------------------------
// Launch
// ---------------------------------------------------------------------------
extern "C" void kernel_launch(void* const* d_in, const int* in_sizes, int n_in,
                              void* d_out, int out_size, void* d_ws, size_t ws_size,
                              hipStream_t stream) {
    const float* x    = (const float*)d_in[0];
    const int*   ei   = (const int*)d_in[1];   // [2, E]: src = ei, dst = ei + E
    const float* w_l1 = (const float*)d_in[2];
    const float* b_l1 = (const float*)d_in[3];
    const float* w_r1 = (const float*)d_in[4];
    const float* w_l2 = (const float*)d_in[5];
    const float* b_l2 = (const float*)d_in[6];
    const float* w_r2 = (const float*)d_in[7];
    float* out = (float*)d_out;

    const int* src = ei;
    const int* dst = ei + N_EDGES;

    int* deg        = (int*)d_ws;                    // N
    int* ex         = deg + N_NODES;                 // N
    int* blk_sum    = ex + N_NODES;                  // 128
    int* blk_off    = blk_sum + 128;                 // 128
    int* row_ptr    = blk_off + 128;                 // N + 1
    int* cursor     = row_ptr + (N_NODES + 1);       // N
    int* sorted_src = cursor + N_NODES;              // E
    float* h        = (float*)(sorted_src + N_EDGES);        // N * D fp32
    unsigned short* xb = (unsigned short*)(h + (size_t)N_NODES * D);   // N * D bf16
    unsigned short* hb = xb + (size_t)N_NODES * D;                     // N * D bf16

    hipMemsetAsync(deg, 0, (size_t)N_NODES * sizeof(int), stream);

    dim3 blk(256);
    cast_kernel<<<dim3((N_NODES * D / 4 + 255) / 256), blk, 0, stream>>>(x, xb);
    degree_kernel<<<dim3((N_EDGES + 255) / 256), blk, 0, stream>>>(dst, deg);
    scan_blocks<<<dim3(N_SCAN_BLKS), dim3(SCAN_BLK), 0, stream>>>(deg, ex, blk_sum);
    scan_partials<<<dim3(1), dim3(128), 0, stream>>>(blk_sum, blk_off);
    finalize_rowptr<<<dim3((N_NODES + 1 + 255) / 256), blk, 0, stream>>>(ex, blk_off, row_ptr, cursor);
    fill_kernel<<<dim3((N_EDGES + 255) / 256), blk, 0, stream>>>(src, dst, cursor, sorted_src);

    dim3 lblk(NWAVES * 64);
    dim3 lgrid((N_NODES + NWAVES - 1) / NWAVES);
    sage_layer<<<lgrid, lblk, 0, stream>>>(row_ptr, sorted_src, xb, x, w_l1, b_l1, w_r1,
                                           h, hb, /*relu=*/1);
    sage_layer<<<lgrid, lblk, 0, stream>>>(row_ptr, sorted_src, hb, h, w_l2, b_l2, w_r2,
                                           out, (unsigned short*)nullptr, /*relu=*/0);
}

// Round 5
// 331.240 us; speedup vs baseline: 1.6096x; 1.4934x over previous
//
#include <hip/hip_runtime.h>

#define N_NODES 100000
#define N_EDGES 1600000
#define D 64
#define NWAVES 16
#define WSTRIDE 68   // 68 mod 32 = 4 -> b128 start banks tile all 32 banks

#define BSHIFT 7                                   // 128 nodes per bucket
#define BNODES (1 << BSHIFT)                       // 128
#define NB ((N_NODES + BNODES - 1) / BNODES)       // 782 buckets
#define PB 128                                     // partition blocks
#define TILE ((N_EDGES + PB - 1) / PB)             // 12500 edges per block
#define TBL (NB * PB)                              // 100096
#define SCAN_BLK 1024
#define SCAN_GRID ((TBL + SCAN_BLK - 1) / SCAN_BLK)  // 98
#define MAXB 4096                                  // LDS staging cap (mean 2048, sd 45)

// round-to-nearest-even fp32 -> bf16 bits
__device__ __forceinline__ unsigned short f2bf(float f) {
    unsigned u = __float_as_uint(f);
    u = (u + 0x7fffu + ((u >> 16) & 1u)) >> 16;
    return (unsigned short)u;
}

// accumulate 4 bf16 (packed in uint2) into float4
__device__ __forceinline__ void acc_bf16x4(float4& a, uint2 v) {
    a.x += __uint_as_float(v.x << 16);
    a.y += __uint_as_float(v.x & 0xffff0000u);
    a.z += __uint_as_float(v.y << 16);
    a.w += __uint_as_float(v.y & 0xffff0000u);
}

__device__ __forceinline__ float4 bf16x4_to_f4(uint2 v) {
    float4 r;
    r.x = __uint_as_float(v.x << 16);
    r.y = __uint_as_float(v.x & 0xffff0000u);
    r.z = __uint_as_float(v.y << 16);
    r.w = __uint_as_float(v.y & 0xffff0000u);
    return r;
}

// ---------------------------------------------------------------------------
// 0) Cast x (fp32) -> xb (bf16)
// ---------------------------------------------------------------------------
__global__ __launch_bounds__(256) void cast_kernel(const float* __restrict__ x,
                                                   unsigned short* __restrict__ xb) {
    int i = blockIdx.x * blockDim.x + threadIdx.x;
    if (i < N_NODES * D / 4) {
        float4 v = ((const float4*)x)[i];
        ushort4 o;
        o.x = f2bf(v.x); o.y = f2bf(v.y); o.z = f2bf(v.z); o.w = f2bf(v.w);
        ((ushort4*)xb)[i] = o;
    }
}

// ---------------------------------------------------------------------------
// 1) Per-(block,bucket) histogram of dst buckets -> table[bucket][block]
// ---------------------------------------------------------------------------
__global__ __launch_bounds__(1024) void p1_hist(const int* __restrict__ dst,
                                                int* __restrict__ table) {
    __shared__ int hist[NB];
    for (int i = threadIdx.x; i < NB; i += 1024) hist[i] = 0;
    __syncthreads();
    int lo = blockIdx.x * TILE;
    int hi = min(lo + TILE, N_EDGES);
    for (int e = lo + threadIdx.x; e < hi; e += 1024)
        atomicAdd(&hist[dst[e] >> BSHIFT], 1);
    __syncthreads();
    for (int b = threadIdx.x; b < NB; b += 1024)
        table[b * PB + blockIdx.x] = hist[b];
}

// ---------------------------------------------------------------------------
// 2) Exclusive scan of the TBL-entry table (in place: each block reads its
//    elements before any write; blocks touch disjoint ranges).
// ---------------------------------------------------------------------------
__global__ __launch_bounds__(SCAN_BLK) void scan_blocks_n(int* __restrict__ buf,
                                                          int* __restrict__ blk_sum,
                                                          int n) {
    __shared__ int tmp[SCAN_BLK];
    int i = blockIdx.x * SCAN_BLK + threadIdx.x;
    int v = (i < n) ? buf[i] : 0;
    int val = v;
    tmp[threadIdx.x] = val;
    __syncthreads();
    for (int off = 1; off < SCAN_BLK; off <<= 1) {
        int t = (threadIdx.x >= off) ? tmp[threadIdx.x - off] : 0;
        __syncthreads();
        val += t;
        tmp[threadIdx.x] = val;
        __syncthreads();
    }
    if (i < n) buf[i] = val - v;                 // exclusive
    if (threadIdx.x == SCAN_BLK - 1) blk_sum[blockIdx.x] = val;
}

__global__ __launch_bounds__(128) void scan_partials(const int* __restrict__ blk_sum,
                                                     int* __restrict__ blk_off, int nb) {
    __shared__ int t[128];
    int i = threadIdx.x;
    int v = (i < nb) ? blk_sum[i] : 0;
    int val = v;
    t[i] = val;
    __syncthreads();
    for (int off = 1; off < 128; off <<= 1) {
        int u = (i >= off) ? t[i - off] : 0;
        __syncthreads();
        val += u;
        t[i] = val;
        __syncthreads();
    }
    if (i < nb) blk_off[i] = val - v;
}

__global__ __launch_bounds__(256) void scan_finalize(int* __restrict__ buf,
                                                     const int* __restrict__ blk_off,
                                                     int n) {
    int i = blockIdx.x * 256 + threadIdx.x;
    if (i < n) buf[i] += blk_off[i >> 10];
}

// ---------------------------------------------------------------------------
// 3) Partition scatter: packed (src<<7 | local_dst) into per-(block,bucket)
//    contiguous runs. Each run is written by exactly one block (one XCD), so
//    its L2 accumulates full lines -> ~no write amplification.
// ---------------------------------------------------------------------------
__global__ __launch_bounds__(1024) void p1_scatter(const int* __restrict__ src,
                                                   const int* __restrict__ dst,
                                                   const int* __restrict__ table,
                                                   int* __restrict__ part) {
    __shared__ int cur[NB];
    for (int b = threadIdx.x; b < NB; b += 1024)
        cur[b] = table[b * PB + blockIdx.x];
    __syncthreads();
    int lo = blockIdx.x * TILE;
    int hi = min(lo + TILE, N_EDGES);
    for (int e = lo + threadIdx.x; e < hi; e += 1024) {
        int dd = dst[e];
        int b = dd >> BSHIFT;
        int p = atomicAdd(&cur[b], 1);
        part[p] = (src[e] << BSHIFT) | (dd & (BNODES - 1));
    }
}

// ---------------------------------------------------------------------------
// 4) Per-bucket sort: one block per bucket. LDS-stage edges, node histogram +
//    wave scan -> row_ptr (replaces degree/scan/finalize kernels), rank-
//    scatter in LDS, coalesced flush of sorted_src.
// ---------------------------------------------------------------------------
__global__ __launch_bounds__(1024) void p2_sort(const int* __restrict__ table,
                                                const int* __restrict__ part,
                                                int* __restrict__ row_ptr,
                                                int* __restrict__ sorted_src) {
    __shared__ int in_buf[MAXB];
    __shared__ int out_buf[MAXB];
    __shared__ int hist[BNODES];
    __shared__ int exs[BNODES];
    __shared__ int cursor[BNODES];

    int k = blockIdx.x;
    int base = table[k * PB];
    int end  = (k < NB - 1) ? table[(k + 1) * PB] : N_EDGES;
    int count = end - base;
    int tid = threadIdx.x;

    for (int i = tid; i < BNODES; i += 1024) hist[i] = 0;
    __syncthreads();

    if (count <= MAXB) {
        for (int i = tid; i < count; i += 1024) {
            int w = part[base + i];
            in_buf[i] = w;
            atomicAdd(&hist[w & (BNODES - 1)], 1);
        }
        __syncthreads();
        if (tid < 64) {                       // wave-0 exclusive scan of 128
            int a = hist[2 * tid], b = hist[2 * tid + 1];
            int s = a + b, incl = s;
            for (int off = 1; off < 64; off <<= 1) {
                int t = __shfl_up(incl, off, 64);
                if (tid >= off) incl += t;
            }
            int excl = incl - s;
            exs[2 * tid] = excl;
            exs[2 * tid + 1] = excl + a;
        }
        __syncthreads();
        if (tid < BNODES) {
            int node = k * BNODES + tid;
            if (node < N_NODES) row_ptr[node] = base + exs[tid];
            cursor[tid] = exs[tid];
        }
        if (tid == 0 && k == NB - 1) row_ptr[N_NODES] = N_EDGES;
        __syncthreads();
        for (int i = tid; i < count; i += 1024) {
            int w = in_buf[i];
            int r = atomicAdd(&cursor[w & (BNODES - 1)], 1);
            out_buf[r] = w >> BSHIFT;
        }
        __syncthreads();
        for (int i = tid; i < count; i += 1024)
            sorted_src[base + i] = out_buf[i];
    } else {
        // Fallback (statistically unreachable: mean 2048, sd 45, cap 4096).
        for (int i = tid; i < count; i += 1024)
            atomicAdd(&hist[part[base + i] & (BNODES - 1)], 1);
        __syncthreads();
        if (tid < 64) {
            int a = hist[2 * tid], b = hist[2 * tid + 1];
            int s = a + b, incl = s;
            for (int off = 1; off < 64; off <<= 1) {
                int t = __shfl_up(incl, off, 64);
                if (tid >= off) incl += t;
            }
            int excl = incl - s;
            exs[2 * tid] = excl;
            exs[2 * tid + 1] = excl + a;
        }
        __syncthreads();
        if (tid < BNODES) {
            int node = k * BNODES + tid;
            if (node < N_NODES) row_ptr[node] = base + exs[tid];
            cursor[tid] = exs[tid];
        }
        if (tid == 0 && k == NB - 1) row_ptr[N_NODES] = N_EDGES;
        __syncthreads();
        for (int i = tid; i < count; i += 1024) {
            int w = part[base + i];
            int r = atomicAdd(&cursor[w & (BNODES - 1)], 1);
            sorted_src[base + r] = w >> BSHIFT;
        }
    }
}

// ---------------------------------------------------------------------------
// 5) Fused SAGE layer (gather bf16, accumulate/GEMM fp32). Self rows also
//    bf16 (featb). Writes fp32 out and/or bf16 outb.
// ---------------------------------------------------------------------------
__global__ __launch_bounds__(NWAVES * 64) void sage_layer(
    const int* __restrict__ row_ptr, const int* __restrict__ nbr,
    const unsigned short* __restrict__ featb,
    const float* __restrict__ w_l, const float* __restrict__ b_l,
    const float* __restrict__ w_r,
    float* __restrict__ out,
    unsigned short* __restrict__ outb,
    int apply_relu)
{
    __shared__ float wl_s[D * WSTRIDE];
    __shared__ float wr_s[D * WSTRIDE];
    __shared__ float bias[D];
    __shared__ float mean_s[NWAVES][D];
    __shared__ float x_s[NWAVES][D];

    int tid = threadIdx.x;
    for (int i = tid; i < D * D; i += NWAVES * 64) {
        int o = i >> 6, k = i & 63;
        wl_s[o * WSTRIDE + k] = w_l[i];
        wr_s[o * WSTRIDE + k] = w_r[i];
    }
    if (tid < D) bias[tid] = b_l[tid];
    __syncthreads();

    int wave = tid >> 6;
    int lane = tid & 63;
    int node = blockIdx.x * NWAVES + wave;
    if (node >= N_NODES) return;

    int g = lane >> 4;       // neighbor group 0..3
    int c = lane & 15;       // column quad 0..15

    int begin = row_ptr[node];
    int end   = row_ptr[node + 1];

    float4 acc4 = make_float4(0.f, 0.f, 0.f, 0.f);
    for (int base = begin; base < end; base += 64) {
        int m = end - base; if (m > 64) m = 64;
        int id = (lane < m) ? nbr[base + lane] : 0;
        int j = 0;
        for (; j + 16 <= m; j += 16) {
            int s0 = __shfl(id, j + g, 64);
            int s1 = __shfl(id, j + 4 + g, 64);
            int s2 = __shfl(id, j + 8 + g, 64);
            int s3 = __shfl(id, j + 12 + g, 64);
            uint2 v0 = *(const uint2*)&featb[(size_t)s0 * D + 4 * c];
            uint2 v1 = *(const uint2*)&featb[(size_t)s1 * D + 4 * c];
            uint2 v2 = *(const uint2*)&featb[(size_t)s2 * D + 4 * c];
            uint2 v3 = *(const uint2*)&featb[(size_t)s3 * D + 4 * c];
            acc_bf16x4(acc4, v0);
            acc_bf16x4(acc4, v1);
            acc_bf16x4(acc4, v2);
            acc_bf16x4(acc4, v3);
        }
        for (; j + 4 <= m; j += 4) {
            int s = __shfl(id, j + g, 64);
            uint2 v = *(const uint2*)&featb[(size_t)s * D + 4 * c];
            acc_bf16x4(acc4, v);
        }
        int rem = m - j;
        if (rem > 0) {
            int s = __shfl(id, j + g, 64);
            if (g < rem) {
                uint2 v = *(const uint2*)&featb[(size_t)s * D + 4 * c];
                acc_bf16x4(acc4, v);
            }
        }
    }

    acc4.x += __shfl_xor(acc4.x, 16, 64);
    acc4.y += __shfl_xor(acc4.y, 16, 64);
    acc4.z += __shfl_xor(acc4.z, 16, 64);
    acc4.w += __shfl_xor(acc4.w, 16, 64);
    acc4.x += __shfl_xor(acc4.x, 32, 64);
    acc4.y += __shfl_xor(acc4.y, 32, 64);
    acc4.z += __shfl_xor(acc4.z, 32, 64);
    acc4.w += __shfl_xor(acc4.w, 32, 64);

    int   deg = end - begin;
    float inv = 1.0f / fmaxf((float)deg, 1.0f);

    uint2 xv = *(const uint2*)&featb[(size_t)node * D + 4 * c];
    float4 x4 = bf16x4_to_f4(xv);
    if (g == 0) {
        float4 m4 = make_float4(acc4.x * inv, acc4.y * inv, acc4.z * inv, acc4.w * inv);
        *(float4*)&mean_s[wave][4 * c] = m4;
        *(float4*)&x_s[wave][4 * c]    = x4;
    }
    // Wave-local LDS write->read ordering via compiler lgkmcnt.

    int o = lane;
    float acc = bias[o];
    const float4* wl4p = (const float4*)&wl_s[o * WSTRIDE];
    const float4* wr4p = (const float4*)&wr_s[o * WSTRIDE];
    const float4* m4p  = (const float4*)&mean_s[wave][0];
    const float4* x4p  = (const float4*)&x_s[wave][0];
#pragma unroll
    for (int kq = 0; kq < 16; ++kq) {
        float4 wl4 = wl4p[kq];
        float4 wr4 = wr4p[kq];
        float4 m4  = m4p[kq];
        float4 xx4 = x4p[kq];
        acc += m4.x * wl4.x + m4.y * wl4.y + m4.z * wl4.z + m4.w * wl4.w;
        acc += xx4.x * wr4.x + xx4.y * wr4.y + xx4.z * wr4.z + xx4.w * wr4.w;
    }
    if (apply_relu) acc = fmaxf(acc, 0.0f);
    if (out)  out[(size_t)node * D + o]  = acc;
    if (outb) outb[(size_t)node * D + o] = f2bf(acc);
}

// ---------------------------------------------------------------------------
// Launch
// ---------------------------------------------------------------------------
extern "C" void kernel_launch(void* const* d_in, const int* in_sizes, int n_in,
                              void* d_out, int out_size, void* d_ws, size_t ws_size,
                              hipStream_t stream) {
    const float* x    = (const float*)d_in[0];
    const int*   ei   = (const int*)d_in[1];   // [2, E]: src = ei, dst = ei + E
    const float* w_l1 = (const float*)d_in[2];
    const float* b_l1 = (const float*)d_in[3];
    const float* w_r1 = (const float*)d_in[4];
    const float* w_l2 = (const float*)d_in[5];
    const float* b_l2 = (const float*)d_in[6];
    const float* w_r2 = (const float*)d_in[7];
    float* out = (float*)d_out;

    const int* src = ei;
    const int* dst = ei + N_EDGES;

    // Workspace (~39 MB)
    int* table      = (int*)d_ws;                    // TBL
    int* blk_sum    = table + TBL;                   // 128
    int* blk_off    = blk_sum + 128;                 // 128
    int* row_ptr    = blk_off + 128;                 // N + 1
    int* part       = row_ptr + (N_NODES + 1);       // E (packed src|ldst)
    int* sorted_src = part + N_EDGES;                // E
    unsigned short* xb = (unsigned short*)(sorted_src + N_EDGES);  // N*D bf16
    unsigned short* hb = xb + (size_t)N_NODES * D;                 // N*D bf16

    dim3 b256(256);
    cast_kernel<<<dim3((N_NODES * D / 4 + 255) / 256), b256, 0, stream>>>(x, xb);

    p1_hist<<<dim3(PB), dim3(1024), 0, stream>>>(dst, table);
    scan_blocks_n<<<dim3(SCAN_GRID), dim3(SCAN_BLK), 0, stream>>>(table, blk_sum, TBL);
    scan_partials<<<dim3(1), dim3(128), 0, stream>>>(blk_sum, blk_off, SCAN_GRID);
    scan_finalize<<<dim3((TBL + 255) / 256), b256, 0, stream>>>(table, blk_off, TBL);
    p1_scatter<<<dim3(PB), dim3(1024), 0, stream>>>(src, dst, table, part);
    p2_sort<<<dim3(NB), dim3(1024), 0, stream>>>(table, part, row_ptr, sorted_src);

    dim3 lblk(NWAVES * 64);
    dim3 lgrid((N_NODES + NWAVES - 1) / NWAVES);
    sage_layer<<<lgrid, lblk, 0, stream>>>(row_ptr, sorted_src, xb, w_l1, b_l1, w_r1,
                                           (float*)nullptr, hb, /*relu=*/1);
    sage_layer<<<lgrid, lblk, 0, stream>>>(row_ptr, sorted_src, hb, w_l2, b_l2, w_r2,
                                           out, (unsigned short*)nullptr, /*relu=*/0);
}